// Round 8
// baseline (267.295 us; speedup 1.0000x reference)
//
#include <hip/hip_runtime.h>
#include <hip/hip_bf16.h>
#include <hip/hip_fp8.h>

// ---------------------------------------------------------------------------
// GRACE contrastive loss, MI355X.
//  out = mean_k 0.5*(ln d1_k + ln d2_k) - 2*s12[k,k]
// With M=[n1;n2] (24576x256) everything is row sums of exp(M M^T / tau)
// split by j-half, plus diagonal probes. S symmetric -> upper-triangle
// tiles, each feeding row-sums AND col-sums (R12), col-sums deferred one
// tile (R13).
//
// R14: 4 WAVES/SIMD. All overlap attempts (R6/R10/R11/R13) ran at 2
// waves/SIMD where in-order issue + block-phase-locking leave pipes empty
// (matrix 32us + VALU 45us + idle 45us, no overlap). The one high-
// occupancy test (R8) was confounded by a register spill. Fix without
// touching per-wave footprint: 512-thread blocks, 8 waves in a 4x2 grid
// (wave = 32 rows x 64 cols: aF[2][2]=32 VGPR, acc 8, rs4 8, cs4 16 ->
// ~110 regs < 128). LDS still 2x32KB/block -> 2 blocks/CU -> 16 waves/CU
// = 4 waves/SIMD. Grid 1536x512 = 3 exact residency rounds. Col-sums now
// 4 atomic contributions/col (one per row-band wave) - atomics merge.
// Also: 3 memsets merged into 1 (SS/Rlow/Rhigh contiguous).
// Tripwire: VGPR~84 or WRITE>>25MB = spill = experiment invalid.
// ---------------------------------------------------------------------------

#define NROWS 12288
#define TWO_N 24576
#define KDIM 256
#define BM 128
#define BN 128
#define BK 32
#define BJ 128
#define NTILE 192   /* 24576 / 128 row-tiles */
#define PAIRS 96
#define SLOTS 16
#define FB 48                   /* finalize partial blocks */
#define LOG2E 1.4426950408889634f
#define SIMSCALE 1.6986436f     /* sqrt(2*log2(e)); acc = (1/tau)*log2e*s */
#define LN2F 0.6931471805599453f

#if __has_builtin(__builtin_amdgcn_exp2f)
#define EXP2F(x) __builtin_amdgcn_exp2f(x)
#else
#define EXP2F(x) exp2f(x)
#endif

typedef __bf16 bf16x8 __attribute__((ext_vector_type(8)));
typedef __bf16 bf16x4v __attribute__((ext_vector_type(4)));
typedef float f32x4 __attribute__((ext_vector_type(4)));
typedef int i32x4 __attribute__((ext_vector_type(4)));
typedef int i32x8 __attribute__((ext_vector_type(8)));
typedef unsigned char uchar;

typedef const __attribute__((address_space(1))) void* gptr_t;
typedef __attribute__((address_space(3))) void* lptr_t;

// ======== legacy 128x128 bf16 GEMM core (proj1/proj2 only) ================
__device__ __forceinline__ void stage_slab(const __bf16* g, int row0, int kelem,
                                           __bf16* lds, int w, int l) {
#pragma unroll
  for (int t = 0; t < 2; ++t) {
    int chunk = w * 2 + t;
    int r = chunk * 16 + (l >> 2);
    int c = l & 3;
    int src = c ^ (r & 3);
    const __bf16* ga = g + (size_t)(row0 + r) * KDIM + kelem + src * 8;
    __bf16* la = lds + chunk * 512;
    __builtin_amdgcn_global_load_lds((gptr_t)ga, (lptr_t)la, 16, 0, 0);
  }
}

__device__ __forceinline__ bf16x8 read_frag(const __bf16* lds, int rowbase,
                                            int tile, int l) {
  int r = rowbase + tile * 16 + (l & 15);
  int q = l >> 4;
  int blk = q ^ (r & 3);
  return *(const bf16x8*)(lds + r * 32 + blk * 8);
}

__device__ __forceinline__ void gemm_tile_core(const __bf16* A, int arow0,
                                               const __bf16* B, int brow0,
                                               __bf16* As, __bf16* Bs,
                                               f32x4 (&acc)[4][4], int w, int l) {
  const int warow = (w >> 1) * 64;
  const int wbrow = (w & 1) * 64;
#pragma unroll
  for (int ks = 0; ks < KDIM / BK; ++ks) {
    __syncthreads();
    stage_slab(A, arow0, ks * BK, As, w, l);
    stage_slab(B, brow0, ks * BK, Bs, w, l);
    __syncthreads();
    bf16x8 aF[4], bF[4];
#pragma unroll
    for (int mi = 0; mi < 4; ++mi) aF[mi] = read_frag(As, warow, mi, l);
#pragma unroll
    for (int ni = 0; ni < 4; ++ni) bF[ni] = read_frag(Bs, wbrow, ni, l);
#pragma unroll
    for (int mi = 0; mi < 4; ++mi)
#pragma unroll
      for (int ni = 0; ni < 4; ++ni)
        acc[mi][ni] = __builtin_amdgcn_mfma_f32_16x16x32_bf16(
            aF[mi], bF[ni], acc[mi][ni], 0, 0, 0);
  }
}

// ---------------------------------------------------------------------------
// one launch: cast z1, z2, W1, W2 to bf16 (float4 granules)
__global__ void cast_all_kernel(const float* __restrict__ z1,
                                const float* __restrict__ z2,
                                const float* __restrict__ W1,
                                const float* __restrict__ W2,
                                __bf16* __restrict__ Zb,
                                __bf16* __restrict__ W1b,
                                __bf16* __restrict__ W2b) {
  const int n4z = NROWS * KDIM / 4;  // 786432
  const int n4w = KDIM * KDIM / 4;   // 16384
  int i = blockIdx.x * blockDim.x + threadIdx.x;
  const float* src;
  __bf16* dst;
  int j;
  if (i < n4z) {
    src = z1; dst = Zb; j = i;
  } else if (i < 2 * n4z) {
    src = z2; dst = Zb + (size_t)NROWS * KDIM; j = i - n4z;
  } else if (i < 2 * n4z + n4w) {
    src = W1; dst = W1b; j = i - 2 * n4z;
  } else if (i < 2 * n4z + 2 * n4w) {
    src = W2; dst = W2b; j = i - 2 * n4z - n4w;
  } else {
    return;
  }
  float4 v = *(const float4*)(src + (size_t)j * 4);
  bf16x4v o;
  o[0] = (__bf16)v.x; o[1] = (__bf16)v.y; o[2] = (__bf16)v.z; o[3] = (__bf16)v.w;
  *(bf16x4v*)(dst + (size_t)j * 4) = o;
}

// T = ELU(Z @ W1^T + b1), stored bf16
__global__ __launch_bounds__(256, 2) void proj1_kernel(
    const __bf16* __restrict__ Zb, const __bf16* __restrict__ W1b,
    const float* __restrict__ b1, __bf16* __restrict__ Tb) {
  __shared__ __align__(16) __bf16 As[BM * BK];
  __shared__ __align__(16) __bf16 Bs[BN * BK];
  int w = threadIdx.x >> 6, l = threadIdx.x & 63;
  int i0 = blockIdx.x * BM, j0 = blockIdx.y * BN;
  int warow = (w >> 1) * 64, wbrow = (w & 1) * 64;
  f32x4 acc[4][4] = {};
  gemm_tile_core(Zb, i0, W1b, j0, As, Bs, acc, w, l);
  float bias[4];
#pragma unroll
  for (int ni = 0; ni < 4; ++ni) bias[ni] = b1[j0 + wbrow + ni * 16 + (l & 15)];
#pragma unroll
  for (int mi = 0; mi < 4; ++mi)
#pragma unroll
    for (int ni = 0; ni < 4; ++ni)
#pragma unroll
      for (int v = 0; v < 4; ++v) {
        int row = i0 + warow + mi * 16 + (l >> 4) * 4 + v;
        int col = j0 + wbrow + ni * 16 + (l & 15);
        float x = acc[mi][ni][v] + bias[ni];
        x = x > 0.f ? x : (EXP2F(x * LOG2E) - 1.f);  // ELU
        Tb[(size_t)row * KDIM + col] = (__bf16)x;
      }
}

// H = T @ W2^T + b2 (fp32), plus per-row sum of squares via atomics
__global__ __launch_bounds__(256, 2) void proj2_kernel(
    const __bf16* __restrict__ Tb, const __bf16* __restrict__ W2b,
    const float* __restrict__ b2, float* __restrict__ H,
    float* __restrict__ SS) {
  __shared__ __align__(16) __bf16 As[BM * BK];
  __shared__ __align__(16) __bf16 Bs[BN * BK];
  int w = threadIdx.x >> 6, l = threadIdx.x & 63;
  int i0 = blockIdx.x * BM, j0 = blockIdx.y * BN;
  int warow = (w >> 1) * 64, wbrow = (w & 1) * 64;
  f32x4 acc[4][4] = {};
  gemm_tile_core(Tb, i0, W2b, j0, As, Bs, acc, w, l);
  float bias[4];
#pragma unroll
  for (int ni = 0; ni < 4; ++ni) bias[ni] = b2[j0 + wbrow + ni * 16 + (l & 15)];
  float ss[4][4] = {};
#pragma unroll
  for (int mi = 0; mi < 4; ++mi)
#pragma unroll
    for (int ni = 0; ni < 4; ++ni)
#pragma unroll
      for (int v = 0; v < 4; ++v) {
        int row = i0 + warow + mi * 16 + (l >> 4) * 4 + v;
        int col = j0 + wbrow + ni * 16 + (l & 15);
        float x = acc[mi][ni][v] + bias[ni];
        H[(size_t)row * KDIM + col] = x;
        ss[mi][v] += x * x;
      }
#pragma unroll
  for (int mi = 0; mi < 4; ++mi)
#pragma unroll
    for (int v = 0; v < 4; ++v) {
      float x = ss[mi][v];
      x += __shfl_xor(x, 1, 64);
      x += __shfl_xor(x, 2, 64);
      x += __shfl_xor(x, 4, 64);
      x += __shfl_xor(x, 8, 64);
      if ((l & 15) == 0)
        atomicAdd(&SS[i0 + warow + mi * 16 + (l >> 4) * 4 + v], x);
    }
}

// pack 4 floats -> 4 fp8 e4m3 bytes
__device__ __forceinline__ unsigned int pack4_fp8(float a, float b, float c,
                                                  float d) {
#if __has_builtin(__builtin_amdgcn_cvt_pk_fp8_f32)
  int v = 0;
  v = __builtin_amdgcn_cvt_pk_fp8_f32(a, b, v, false);
  v = __builtin_amdgcn_cvt_pk_fp8_f32(c, d, v, true);
  return (unsigned int)v;
#else
  __hip_fp8_e4m3 qa(a), qb(b), qc(c), qd(d);
  return (unsigned int)qa.__x | ((unsigned int)qb.__x << 8) |
         ((unsigned int)qc.__x << 16) | ((unsigned int)qd.__x << 24);
#endif
}

// Nq = fp8(H * rsqrt(SS[row]) * SIMSCALE) — 8 elements per thread.
// SIMSCALE folds the (1/tau)*log2(e) exponent scale into the data:
// dot(Nq_i, Nq_j) = 2.8854 * cos_ij, so exp2(acc) = exp(cos/tau).
__global__ void norm_kernel(const float* __restrict__ H,
                            const float* __restrict__ SS,
                            uchar* __restrict__ Nq) {
  int i = blockIdx.x * blockDim.x + threadIdx.x;
  size_t idx = (size_t)i * 8;
  if (idx >= (size_t)TWO_N * KDIM) return;
  int row = (int)(idx >> 8);
  float inv = rsqrtf(SS[row]) * SIMSCALE;
  float4 h0 = *(const float4*)(H + idx);
  float4 h1 = *(const float4*)(H + idx + 4);
  uint2 o;
  o.x = pack4_fp8(h0.x * inv, h0.y * inv, h0.z * inv, h0.w * inv);
  o.y = pack4_fp8(h1.x * inv, h1.y * inv, h1.z * inv, h1.w * inv);
  *(uint2*)(Nq + idx) = o;
}

// ======== R14 sim kernel: 512 threads, 8 waves (4x2), 4 waves/SIMD =========
// Pair p = (I1=p, I2=191-p): flattened F in [0,193):
//   F <  L1=192-I1 : A-tile = I1, J-tile = I1 + F   (seg1)
//   F >= L1        : A-tile = I2, J-tile = F - 1    (seg2)
// Wave (wr = w>>1 in 0..3, wc = w&1 in 0..1): 32 rows x 64 cols.
// Off-diag tile: row-sums (regs, flushed on half/segment switch) and
// col-sums (cs4[nj] regs; hsum+shfl+atomic deferred to next iteration).
// Diag tile: row-sums only.
__global__ __launch_bounds__(512, 2) void sim_kernel(
    const uchar* __restrict__ Nq, float* __restrict__ Rlow,
    float* __restrict__ Rhigh, float* __restrict__ Dsame,
    float* __restrict__ Dcross) {
  __shared__ __align__(16) uchar Bs[2][BJ * KDIM];  // 2 x 32KB
  int tid = threadIdx.x;
  int w = tid >> 6, l = tid & 63;
  int q = l >> 4;
  int rx = l & 15;
  int b = blockIdx.x;
  int p = b >> 4;              // pair index 0..95
  int s = b & 15;              // slot within pair
  const int I1 = p, I2 = NTILE - 1 - p;
  const int L1 = NTILE - I1;   // seg1 length
  int fstart = (s == 0) ? 0 : 13 + (s - 1) * 12;
  int fend = fstart + ((s == 0) ? 13 : 12);
  int warow = (w >> 1) * 32;   // A rows of this wave (32-row band)
  int wbcol = (w & 1) * 64;    // B cols of this wave

  // per-lane staging offsets within a 128x256B tile (source-side XOR
  // swizzle: LDS slot c of row r holds global 16B-block c ^ (r&15)).
  unsigned off0[4];
#pragma unroll
  for (int t = 0; t < 4; ++t) {
    int ch = w * 4 + t;            // wave-uniform chunk 0..31 (1KB each)
    int r = ch * 4 + q;            // row 0..127 (4 rows per chunk)
    int src = rx ^ (r & 15);       // global k-block landing in slot rx
    off0[t] = (unsigned)(r * KDIM + src * 16);
  }
  auto jtile_of = [&](int F) { return (F < L1) ? (I1 + F) : (F - 1); };
  auto atile_of = [&](int F) { return (F < L1) ? I1 : I2; };

  auto stage = [&](int F, int bi) {
    unsigned jo = (unsigned)(jtile_of(F) * (BM * KDIM));
#pragma unroll
    for (int t = 0; t < 4; ++t) {
      const uchar* ga = Nq + (size_t)(jo + off0[t]);
      uchar* la = Bs[bi] + (w * 4 + t) * 1024;  // wave-uniform base
      __builtin_amdgcn_global_load_lds((gptr_t)ga, (lptr_t)la, 16, 0, 0);
    }
  };

  // ---- A fragments: aF[mi][hf], 4 x i32x8 = 32 VGPRs ----
  i32x8 aF[2][2];
  auto load_aF = [&](int Atile) {
#pragma unroll
    for (int mi = 0; mi < 2; ++mi) {
      const uchar* ap = Nq +
          (size_t)(Atile * BM + warow + mi * 16 + rx) * KDIM + q * 32;
#pragma unroll
      for (int hf = 0; hf < 2; ++hf)
        aF[mi][hf] = *(const i32x8*)(ap + hf * 128);
    }
  };

  // lane-constant LDS read offsets for the B fragments (rx nj-invariant;
  // nj advances by 16 rows = 4096 bytes, an imm offset).
  int rdo[2][2];
#pragma unroll
  for (int hf = 0; hf < 2; ++hf) {
    int kb = hf * 8 + 2 * q;
    rdo[hf][0] = (kb ^ rx) << 4;
    rdo[hf][1] = ((kb + 1) ^ rx) << 4;
  }

  f32x4 rs4[2] = {};  // running row sums for current (A, half(J)) span
  f32x4 cs4[4];       // col partials of the pending tile
  int pend = 0;       // pending col-sum flush?
  float* pendR = nullptr;
  int pendBase = 0;

  auto flushrs = [&](int Atile, int h) {
    float* R = h ? Rhigh : Rlow;
#pragma unroll
    for (int mi = 0; mi < 2; ++mi)
#pragma unroll
      for (int v = 0; v < 4; ++v) {
        float x = rs4[mi][v];
        x += __shfl_xor(x, 1, 64);
        x += __shfl_xor(x, 2, 64);
        x += __shfl_xor(x, 4, 64);
        x += __shfl_xor(x, 8, 64);
        if (rx == 0)
          atomicAdd(&R[Atile * BM + warow + mi * 16 + q * 4 + v], x);
        rs4[mi][v] = 0.f;
      }
  };
  auto flushcs = [&]() {
#pragma unroll
    for (int nj = 0; nj < 4; ++nj) {
      float c = (cs4[nj][0] + cs4[nj][1]) + (cs4[nj][2] + cs4[nj][3]);
      c += __shfl_xor(c, 16, 64);
      c += __shfl_xor(c, 32, 64);
      if (q == 0)
        atomicAdd(&pendR[pendBase + wbcol + nj * 16 + rx], c);
    }
    pend = 0;
  };

  const f32x4 Z4 = {0.f, 0.f, 0.f, 0.f};

  int Aprev = atile_of(fstart);
  int hprev = (jtile_of(fstart) >= NTILE / 2) ? 1 : 0;
  load_aF(Aprev);
  stage(fstart, 0);  // prologue

  for (int f = fstart; f < fend; ++f) {
    int bi = (f - fstart) & 1;
    __syncthreads();                       // stage(f) done; prev readers done
    if (f + 1 < fend) stage(f + 1, bi ^ 1);  // drains at NEXT barrier
    if (pend) flushcs();  // tile f-1's col-sums; atomics drain at barrier f+1

    int Atile = atile_of(f);
    int Jt = jtile_of(f);
    int h = (Jt >= NTILE / 2) ? 1 : 0;
    if (Atile != Aprev) {          // segment switch (<=1 per block)
      flushrs(Aprev, hprev);
      load_aF(Atile);
      Aprev = Atile;
      hprev = h;
    } else if (h != hprev) {       // half(J) crossing (<=1 per segment)
      flushrs(Aprev, hprev);
      hprev = h;
    }

    bool dsame = (Jt == Atile);                // diagonal tile
    bool dcross = (Jt == Atile + NTILE / 2);   // (k, k+N) tile
    float* Rcol = (Atile >= NTILE / 2) ? Rhigh : Rlow;  // col-sum target

    // tile-constant B-fragment pointers (nj advances via imm offset 4096)
    const uchar* bL = Bs[bi] + (size_t)(wbcol + rx) * KDIM;
    const uchar* p00 = bL + rdo[0][0];
    const uchar* p01 = bL + rdo[0][1];
    const uchar* p10 = bL + rdo[1][0];
    const uchar* p11 = bL + rdo[1][1];

#pragma unroll
    for (int nj = 0; nj < 4; ++nj) {
      const int no = nj * 4096;
      i32x8 bF0 = __builtin_shufflevector(*(const i32x4*)(p00 + no),
                                          *(const i32x4*)(p01 + no),
                                          0, 1, 2, 3, 4, 5, 6, 7);
      i32x8 bF1 = __builtin_shufflevector(*(const i32x4*)(p10 + no),
                                          *(const i32x4*)(p11 + no),
                                          0, 1, 2, 3, 4, 5, 6, 7);
      f32x4 acc[2];
#pragma unroll
      for (int mi = 0; mi < 2; ++mi)
        acc[mi] = __builtin_amdgcn_mfma_scale_f32_16x16x128_f8f6f4(
            aF[mi][0], bF0, Z4, 0, 0, 0, 0x7F7F7F7F, 0, 0x7F7F7F7F);
#pragma unroll
      for (int mi = 0; mi < 2; ++mi)
        acc[mi] = __builtin_amdgcn_mfma_scale_f32_16x16x128_f8f6f4(
            aF[mi][1], bF1, acc[mi], 0, 0, 0, 0x7F7F7F7F, 0, 0x7F7F7F7F);
      // exp epilogue: vector adds into row sums + col partials
#pragma unroll
      for (int mi = 0; mi < 2; ++mi) {
        f32x4 e4;
        e4[0] = EXP2F(acc[mi][0]);
        e4[1] = EXP2F(acc[mi][1]);
        e4[2] = EXP2F(acc[mi][2]);
        e4[3] = EXP2F(acc[mi][3]);
        rs4[mi] += e4;
        cs4[nj] = (mi == 0) ? e4 : (cs4[nj] + e4);
      }

      if (dsame | dcross) {       // wave-uniform, rare
        float* D = dsame ? Dsame : Dcross;
#pragma unroll
        for (int mi = 0; mi < 2; ++mi)
#pragma unroll
          for (int v = 0; v < 4; ++v) {
            int li = warow + mi * 16 + q * 4 + v;
            int lj = wbcol + nj * 16 + rx;
            if (li == lj) D[Atile * BM + li] = acc[mi][v];
          }
      }
    }

    if (!dsame) {  // schedule this tile's col-sums for the next iteration
      pend = 1;
      pendR = Rcol;
      pendBase = Jt * BM;
    }
  }

  if (pend) flushcs();    // last tile's col-sums
  flushrs(Aprev, hprev);  // final row-sum flush
}

// Dsame/Dcross hold acc = (1/tau)*log2e * s. exp(s/tau) = exp2(acc);
// -2*s = -ln2 * acc.  48 blocks x 256 threads = 12288 rows exactly.
__global__ void finalize1_kernel(const float* __restrict__ Rlow,
                                 const float* __restrict__ Rhigh,
                                 const float* __restrict__ Dsame,
                                 const float* __restrict__ Dcross,
                                 float* __restrict__ partial) {
  __shared__ float red[256];
  int k = blockIdx.x * 256 + threadIdx.x;
  float d1 = Rlow[k] + Rhigh[k] - EXP2F(Dsame[k]);
  float d2 = Rhigh[NROWS + k] + Rlow[NROWS + k] - EXP2F(Dsame[NROWS + k]);
  float acc = 0.5f * (logf(d1) + logf(d2)) - LN2F * Dcross[k];
  red[threadIdx.x] = acc;
  __syncthreads();
  for (int s = 128; s > 0; s >>= 1) {
    if (threadIdx.x < s) red[threadIdx.x] += red[threadIdx.x + s];
    __syncthreads();
  }
  if (threadIdx.x == 0) partial[blockIdx.x] = red[0];
}

__global__ void finalize2_kernel(const float* __restrict__ partial,
                                 float* __restrict__ out) {
  float x = (threadIdx.x < FB) ? partial[threadIdx.x] : 0.f;
#pragma unroll
  for (int s = 32; s > 0; s >>= 1) x += __shfl_down(x, s, 64);
  if (threadIdx.x == 0) out[0] = x / (float)NROWS;
}

// ---------------------------------------------------------------------------
extern "C" void kernel_launch(void* const* d_in, const int* in_sizes, int n_in,
                              void* d_out, int out_size, void* d_ws,
                              size_t ws_size, hipStream_t stream) {
  const float* z1 = (const float*)d_in[0];
  const float* z2 = (const float*)d_in[1];
  const float* W1 = (const float*)d_in[2];
  const float* b1 = (const float*)d_in[3];
  const float* W2 = (const float*)d_in[4];
  const float* b2 = (const float*)d_in[5];
  float* out = (float*)d_out;

  char* ws = (char*)d_ws;
  size_t off = 0;
  auto alloc = [&](size_t bytes) -> void* {
    void* p = ws + off;
    off += (bytes + 255) & ~(size_t)255;
    return p;
  };
  __bf16* Zb   = (__bf16*)alloc((size_t)TWO_N * KDIM * 2); // reused as Nq
  __bf16* W1b  = (__bf16*)alloc((size_t)KDIM * KDIM * 2);
  __bf16* W2b  = (__bf16*)alloc((size_t)KDIM * KDIM * 2);
  __bf16* Tb   = (__bf16*)alloc((size_t)TWO_N * KDIM * 2);
  float*  H    = (float*)alloc((size_t)TWO_N * KDIM * 4);
  float*  SS   = (float*)alloc((size_t)TWO_N * 4);   // SS,Rlow,Rhigh
  float*  Rlow = (float*)alloc((size_t)TWO_N * 4);   //  contiguous
  float*  Rhigh= (float*)alloc((size_t)TWO_N * 4);   //  (one memset)
  float*  Dsame= (float*)alloc((size_t)TWO_N * 4);
  float*  Dcross=(float*)alloc((size_t)NROWS * 4);
  float*  partial=(float*)alloc((size_t)FB * 4);
  uchar*  Nq = (uchar*)Zb;  // Zb dead after proj1; fp8 fits in its footprint

  // SS/Rlow/Rhigh are adjacent 256-aligned allocations of TWO_N*4 bytes
  hipMemsetAsync(SS, 0, (size_t)3 * TWO_N * 4, stream);

  int n4z = NROWS * KDIM / 4;   // 786432
  int n4w = KDIM * KDIM / 4;    // 16384
  int n4all = 2 * n4z + 2 * n4w;
  cast_all_kernel<<<(n4all + 255) / 256, 256, 0, stream>>>(z1, z2, W1, W2, Zb,
                                                           W1b, W2b);

  proj1_kernel<<<dim3(TWO_N / BM, KDIM / BN), 256, 0, stream>>>(Zb, W1b, b1, Tb);
  proj2_kernel<<<dim3(TWO_N / BM, KDIM / BN), 256, 0, stream>>>(Tb, W2b, b2, H, SS);

  int n8n = TWO_N * KDIM / 8;   // 786432
  norm_kernel<<<(n8n + 255) / 256, 256, 0, stream>>>(H, SS, Nq);

  sim_kernel<<<PAIRS * SLOTS, 512, 0, stream>>>(Nq, Rlow, Rhigh, Dsame,
                                                Dcross);
  finalize1_kernel<<<FB, 256, 0, stream>>>(Rlow, Rhigh, Dsame, Dcross, partial);
  finalize2_kernel<<<1, 64, 0, stream>>>(partial, out);
}